// Round 1
// baseline (4000.066 us; speedup 1.0000x reference)
//
#include <hip/hip_runtime.h>
#include <math.h>

#define B 4
#define S 2048
#define E 1024
#define H 16
#define DK 64
#define NROW (B * S)          // 8192 rows

// ---------------------------------------------------------------------------
// GEMM: C[M,E] = A[M,E] @ W[E,E] + bias   (fp32, 64x64 tile, BK=16)
// ---------------------------------------------------------------------------
#define BM 64
#define BN 64
#define BK 16

__global__ __launch_bounds__(256)
void gemm_bias_kernel(const float* __restrict__ A, const float* __restrict__ W,
                      const float* __restrict__ bias, float* __restrict__ C) {
    __shared__ float As[BK][BM + 1];   // +1 pad: break 64-stride bank aliasing
    __shared__ float Ws[BK][BN];

    const int t   = threadIdx.x;
    const int bn0 = blockIdx.x * BN;
    const int bm0 = blockIdx.y * BM;

    const int tx   = t & 15;
    const int ty   = t >> 4;
    const int row0 = ty * 4;
    const int col0 = tx * 4;

    // global-load assignments
    const int am = t >> 2;           // 0..63  (A row within tile)
    const int ak = (t & 3) * 4;      // 0,4,8,12
    const int wk = t >> 4;           // 0..15  (W row within tile)
    const int wn = (t & 15) * 4;     // 0..60

    float acc[4][4] = {};

    for (int k0 = 0; k0 < E; k0 += BK) {
        float4 av = *(const float4*)(A + (size_t)(bm0 + am) * E + k0 + ak);
        As[ak + 0][am] = av.x;
        As[ak + 1][am] = av.y;
        As[ak + 2][am] = av.z;
        As[ak + 3][am] = av.w;
        float4 wv = *(const float4*)(W + (size_t)(k0 + wk) * E + bn0 + wn);
        *(float4*)(&Ws[wk][wn]) = wv;
        __syncthreads();

        #pragma unroll
        for (int k = 0; k < BK; ++k) {
            float a0 = As[k][row0 + 0];
            float a1 = As[k][row0 + 1];
            float a2 = As[k][row0 + 2];
            float a3 = As[k][row0 + 3];
            float w0 = Ws[k][col0 + 0];
            float w1 = Ws[k][col0 + 1];
            float w2 = Ws[k][col0 + 2];
            float w3 = Ws[k][col0 + 3];
            acc[0][0] += a0 * w0; acc[0][1] += a0 * w1; acc[0][2] += a0 * w2; acc[0][3] += a0 * w3;
            acc[1][0] += a1 * w0; acc[1][1] += a1 * w1; acc[1][2] += a1 * w2; acc[1][3] += a1 * w3;
            acc[2][0] += a2 * w0; acc[2][1] += a2 * w1; acc[2][2] += a2 * w2; acc[2][3] += a2 * w3;
            acc[3][0] += a3 * w0; acc[3][1] += a3 * w1; acc[3][2] += a3 * w2; acc[3][3] += a3 * w3;
        }
        __syncthreads();
    }

    float4 bv = *(const float4*)(bias + bn0 + col0);
    #pragma unroll
    for (int i = 0; i < 4; ++i) {
        const size_t row = (size_t)(bm0 + row0 + i);
        float4 cv;
        cv.x = acc[i][0] + bv.x;
        cv.y = acc[i][1] + bv.y;
        cv.z = acc[i][2] + bv.z;
        cv.w = acc[i][3] + bv.w;
        *(float4*)(C + row * E + bn0 + col0) = cv;
    }
}

// ---------------------------------------------------------------------------
// Flash attention: one block = (b, h, 32-query tile); stream 32-key tiles.
// ---------------------------------------------------------------------------
#define BQ  32
#define BKV 32

__global__ __launch_bounds__(256)
void attn_kernel(const float* __restrict__ Q, const float* __restrict__ K,
                 const float* __restrict__ V, float* __restrict__ O) {
    __shared__ float Qs[BQ][DK + 1];    // stride 65: conflict-free column reads
    __shared__ float Ks[BKV][DK + 1];
    __shared__ float Vs[BKV][DK + 1];
    __shared__ float St[BQ][BKV + 1];
    __shared__ float mrow[BQ], lrow[BQ], arow[BQ];

    const int t  = threadIdx.x;
    const int bh = blockIdx.y;          // 0..63
    const int b  = bh >> 4;
    const int h  = bh & (H - 1);
    const int s0 = blockIdx.x * BQ;

    // tile-load mapping (also used for O accumulator ownership)
    const int qr = t >> 3;              // 0..31 : row within tile
    const int d0 = (t & 7) * 8;         // 0..56 : 8-dim group

    // load Q tile (32x64), 8 floats/thread
    {
        const float* p = Q + ((size_t)(b * S + s0 + qr)) * E + h * DK + d0;
        float4 q0 = *(const float4*)(p);
        float4 q1 = *(const float4*)(p + 4);
        Qs[qr][d0 + 0] = q0.x; Qs[qr][d0 + 1] = q0.y; Qs[qr][d0 + 2] = q0.z; Qs[qr][d0 + 3] = q0.w;
        Qs[qr][d0 + 4] = q1.x; Qs[qr][d0 + 5] = q1.y; Qs[qr][d0 + 6] = q1.z; Qs[qr][d0 + 7] = q1.w;
    }
    if (t < BQ) { mrow[t] = -1e30f; lrow[t] = 0.0f; }

    // score mapping: thread computes St[sqr][skc..skc+3]
    const int sqr = t >> 3;
    const int skc = (t & 7) * 4;

    float o[8] = {};

    for (int kt = 0; kt < S / BKV; ++kt) {
        // stage K,V tiles
        {
            const float* kp = K + ((size_t)(b * S + kt * BKV + qr)) * E + h * DK + d0;
            float4 k0 = *(const float4*)(kp);
            float4 k1 = *(const float4*)(kp + 4);
            Ks[qr][d0 + 0] = k0.x; Ks[qr][d0 + 1] = k0.y; Ks[qr][d0 + 2] = k0.z; Ks[qr][d0 + 3] = k0.w;
            Ks[qr][d0 + 4] = k1.x; Ks[qr][d0 + 5] = k1.y; Ks[qr][d0 + 6] = k1.z; Ks[qr][d0 + 7] = k1.w;
            const float* vp = V + ((size_t)(b * S + kt * BKV + qr)) * E + h * DK + d0;
            float4 v0 = *(const float4*)(vp);
            float4 v1 = *(const float4*)(vp + 4);
            Vs[qr][d0 + 0] = v0.x; Vs[qr][d0 + 1] = v0.y; Vs[qr][d0 + 2] = v0.z; Vs[qr][d0 + 3] = v0.w;
            Vs[qr][d0 + 4] = v1.x; Vs[qr][d0 + 5] = v1.y; Vs[qr][d0 + 6] = v1.z; Vs[qr][d0 + 7] = v1.w;
        }
        __syncthreads();

        // scores: 4 dot-products of length 64 per thread
        float sc0 = 0.f, sc1 = 0.f, sc2 = 0.f, sc3 = 0.f;
        #pragma unroll
        for (int d = 0; d < DK; ++d) {
            const float qv = Qs[sqr][d];
            sc0 += qv * Ks[skc + 0][d];
            sc1 += qv * Ks[skc + 1][d];
            sc2 += qv * Ks[skc + 2][d];
            sc3 += qv * Ks[skc + 3][d];
        }
        St[sqr][skc + 0] = sc0 * 0.125f;
        St[sqr][skc + 1] = sc1 * 0.125f;
        St[sqr][skc + 2] = sc2 * 0.125f;
        St[sqr][skc + 3] = sc3 * 0.125f;
        __syncthreads();

        // online softmax per row (32 threads)
        if (t < BQ) {
            const float m_old = mrow[t];
            float mx = m_old;
            #pragma unroll
            for (int k = 0; k < BKV; ++k) mx = fmaxf(mx, St[t][k]);
            float sum = 0.f;
            #pragma unroll
            for (int k = 0; k < BKV; ++k) {
                const float p = __expf(St[t][k] - mx);
                St[t][k] = p;
                sum += p;
            }
            const float alpha = __expf(m_old - mx);
            lrow[t] = lrow[t] * alpha + sum;
            mrow[t] = mx;
            arow[t] = alpha;
        }
        __syncthreads();

        // rescale + PV accumulate
        const float alpha = arow[qr];
        #pragma unroll
        for (int j = 0; j < 8; ++j) o[j] *= alpha;
        #pragma unroll
        for (int kk = 0; kk < BKV; ++kk) {
            const float p = St[qr][kk];
            #pragma unroll
            for (int j = 0; j < 8; ++j) o[j] += p * Vs[kk][d0 + j];
        }
        __syncthreads();
    }

    const float inv_l = 1.0f / lrow[qr];
    float* op = O + ((size_t)(b * S + s0 + qr)) * E + h * DK + d0;
    float4 o0, o1;
    o0.x = o[0] * inv_l; o0.y = o[1] * inv_l; o0.z = o[2] * inv_l; o0.w = o[3] * inv_l;
    o1.x = o[4] * inv_l; o1.y = o[5] * inv_l; o1.z = o[6] * inv_l; o1.w = o[7] * inv_l;
    *(float4*)(op)     = o0;
    *(float4*)(op + 4) = o1;
}

// ---------------------------------------------------------------------------
extern "C" void kernel_launch(void* const* d_in, const int* in_sizes, int n_in,
                              void* d_out, int out_size, void* d_ws, size_t ws_size,
                              hipStream_t stream) {
    const float* x   = (const float*)d_in[0];
    const float* w_q = (const float*)d_in[1];
    const float* b_q = (const float*)d_in[2];
    const float* w_k = (const float*)d_in[3];
    const float* b_k = (const float*)d_in[4];
    const float* w_v = (const float*)d_in[5];
    const float* b_v = (const float*)d_in[6];
    const float* w_o = (const float*)d_in[7];
    const float* b_o = (const float*)d_in[8];
    float* out = (float*)d_out;

    float* ws  = (float*)d_ws;
    float* Qw  = ws;                          // 8M floats = 32 MB
    float* Kw  = Qw + (size_t)NROW * E;
    float* Vw  = Kw + (size_t)NROW * E;
    float* CTX = Vw + (size_t)NROW * E;       // total 128 MB

    dim3 gblk(256);
    dim3 ggrid(E / BN, NROW / BM);            // (16, 128)

    gemm_bias_kernel<<<ggrid, gblk, 0, stream>>>(x, w_q, b_q, Qw);
    gemm_bias_kernel<<<ggrid, gblk, 0, stream>>>(x, w_k, b_k, Kw);
    gemm_bias_kernel<<<ggrid, gblk, 0, stream>>>(x, w_v, b_v, Vw);

    dim3 agrid(S / BQ, B * H);                // (64, 64)
    attn_kernel<<<agrid, dim3(256), 0, stream>>>(Qw, Kw, Vw, CTX);

    gemm_bias_kernel<<<ggrid, gblk, 0, stream>>>(CTX, w_o, b_o, out);
}

// Round 2
// 1315.768 us; speedup vs baseline: 3.0401x; 3.0401x over previous
//
#include <hip/hip_runtime.h>
#include <math.h>

#define B 4
#define S 2048
#define E 1024
#define H 16
#define DK 64
#define NROW (B * S)          // 8192 rows

typedef unsigned short ushort_t;
typedef __attribute__((ext_vector_type(8))) short bf16x8;
typedef __attribute__((ext_vector_type(4))) float f32x4;

__device__ inline ushort_t f2bf(float x) {
    unsigned u = __float_as_uint(x);
    u += 0x7FFFu + ((u >> 16) & 1u);       // round-to-nearest-even
    return (ushort_t)(u >> 16);
}

// ---------------------------------------------------------------------------
// GEMM: fp32 compute, 64x64 tile, BK=16. Three epilogue variants.
// ---------------------------------------------------------------------------
#define BM 64
#define BN 64
#define BK 16

#define GEMM_BODY()                                                             \
    __shared__ float As[BK][BM + 1];                                            \
    __shared__ float Ws[BK][BN];                                                \
    const int t   = threadIdx.x;                                                \
    const int bn0 = blockIdx.x * BN;                                            \
    const int bm0 = blockIdx.y * BM;                                            \
    const int tx   = t & 15;                                                    \
    const int ty   = t >> 4;                                                    \
    const int row0 = ty * 4;                                                    \
    const int col0 = tx * 4;                                                    \
    const int am = t >> 2;                                                      \
    const int ak = (t & 3) * 4;                                                 \
    const int wk = t >> 4;                                                      \
    const int wn = (t & 15) * 4;                                                \
    float acc[4][4] = {};                                                       \
    for (int k0 = 0; k0 < E; k0 += BK) {                                        \
        float4 av = *(const float4*)(A + (size_t)(bm0 + am) * E + k0 + ak);     \
        As[ak + 0][am] = av.x;                                                  \
        As[ak + 1][am] = av.y;                                                  \
        As[ak + 2][am] = av.z;                                                  \
        As[ak + 3][am] = av.w;                                                  \
        float4 wv = *(const float4*)(W + (size_t)(k0 + wk) * E + bn0 + wn);     \
        *(float4*)(&Ws[wk][wn]) = wv;                                           \
        __syncthreads();                                                        \
        _Pragma("unroll")                                                       \
        for (int k = 0; k < BK; ++k) {                                          \
            float a0 = As[k][row0 + 0];                                         \
            float a1 = As[k][row0 + 1];                                         \
            float a2 = As[k][row0 + 2];                                         \
            float a3 = As[k][row0 + 3];                                         \
            float w0 = Ws[k][col0 + 0];                                         \
            float w1 = Ws[k][col0 + 1];                                         \
            float w2 = Ws[k][col0 + 2];                                         \
            float w3 = Ws[k][col0 + 3];                                         \
            acc[0][0] += a0 * w0; acc[0][1] += a0 * w1; acc[0][2] += a0 * w2; acc[0][3] += a0 * w3; \
            acc[1][0] += a1 * w0; acc[1][1] += a1 * w1; acc[1][2] += a1 * w2; acc[1][3] += a1 * w3; \
            acc[2][0] += a2 * w0; acc[2][1] += a2 * w1; acc[2][2] += a2 * w2; acc[2][3] += a2 * w3; \
            acc[3][0] += a3 * w0; acc[3][1] += a3 * w1; acc[3][2] += a3 * w2; acc[3][3] += a3 * w3; \
        }                                                                       \
        __syncthreads();                                                        \
    }

// fp32 output (final projection)
__global__ __launch_bounds__(256)
void gemm_bias_kernel(const float* __restrict__ A, const float* __restrict__ W,
                      const float* __restrict__ bias, float* __restrict__ C) {
    GEMM_BODY()
    float4 bv = *(const float4*)(bias + bn0 + col0);
    #pragma unroll
    for (int i = 0; i < 4; ++i) {
        const size_t row = (size_t)(bm0 + row0 + i);
        float4 cv;
        cv.x = acc[i][0] + bv.x;
        cv.y = acc[i][1] + bv.y;
        cv.z = acc[i][2] + bv.z;
        cv.w = acc[i][3] + bv.w;
        *(float4*)(C + row * E + bn0 + col0) = cv;
    }
}

// bf16 output, row-major (Q, K projections)
__global__ __launch_bounds__(256)
void gemm_bias_bf16_kernel(const float* __restrict__ A, const float* __restrict__ W,
                           const float* __restrict__ bias, ushort_t* __restrict__ C) {
    GEMM_BODY()
    float4 bv = *(const float4*)(bias + bn0 + col0);
    #pragma unroll
    for (int i = 0; i < 4; ++i) {
        const size_t row = (size_t)(bm0 + row0 + i);
        ushort4 pk;
        pk.x = f2bf(acc[i][0] + bv.x);
        pk.y = f2bf(acc[i][1] + bv.y);
        pk.z = f2bf(acc[i][2] + bv.z);
        pk.w = f2bf(acc[i][3] + bv.w);
        *(ushort4*)(C + row * E + bn0 + col0) = pk;
    }
}

// bf16 output, transposed per head: Vt[(b*H+h)*DK + d][s]  (V projection)
__global__ __launch_bounds__(256)
void gemm_bias_bf16_vT_kernel(const float* __restrict__ A, const float* __restrict__ W,
                              const float* __restrict__ bias, ushort_t* __restrict__ C) {
    GEMM_BODY()
    __shared__ ushort_t Ts[BN][BM + 8];    // [col(d)][row(s)], pad 72
    float4 bv = *(const float4*)(bias + bn0 + col0);
    #pragma unroll
    for (int i = 0; i < 4; ++i) {
        Ts[col0 + 0][row0 + i] = f2bf(acc[i][0] + bv.x);
        Ts[col0 + 1][row0 + i] = f2bf(acc[i][1] + bv.y);
        Ts[col0 + 2][row0 + i] = f2bf(acc[i][2] + bv.z);
        Ts[col0 + 3][row0 + i] = f2bf(acc[i][3] + bv.w);
    }
    __syncthreads();
    const int dd = t >> 2;            // 0..63 local col (d)
    const int sl = (t & 3) * 16;      // 0..48 local row chunk
    const int bb = bm0 >> 11;         // batch (2048 rows each)
    const int hh = bn0 >> 6;          // head
    const size_t base = ((size_t)(bb * H + hh) * DK + dd) * S + (bm0 & (S - 1)) + sl;
    uint4 v0 = *(const uint4*)&Ts[dd][sl];
    uint4 v1 = *(const uint4*)&Ts[dd][sl + 8];
    *(uint4*)(C + base)     = v0;
    *(uint4*)(C + base + 8) = v1;
}

// ---------------------------------------------------------------------------
// MFMA flash attention: block = 4 waves, 64 Q-rows; stream 64-row KV tiles.
// Q,K bf16 row-major [row][E]; V bf16 transposed [(b*H+h)*DK + d][s].
// ---------------------------------------------------------------------------
__global__ __launch_bounds__(256)
void attn_mfma_kernel(const ushort_t* __restrict__ Qg, const ushort_t* __restrict__ Kg,
                      const ushort_t* __restrict__ Vtg, float* __restrict__ O) {
    __shared__ ushort_t Qs[64][72];    // [q][d]   pitch 144B -> bank stride 4, 2-way free
    __shared__ ushort_t Ks[64][72];    // [k][d]
    __shared__ ushort_t Vs[64][72];    // [d][k]   (from transposed global V)
    __shared__ ushort_t Pt[64][72];    // [q][k]   bf16 probabilities
    __shared__ float    St[64][66];    // [q][k]   fp32 scores
    __shared__ float    mrow[64], lrow[64], arow[64];

    const int t  = threadIdx.x;
    const int bh = blockIdx.y;                // b*16 + h
    const int b  = bh >> 4;
    const int h  = bh & 15;
    const int s0 = blockIdx.x * 64;

    // staging map: thread covers one row, 16 contiguous elements
    const int srow = t >> 2;
    const int sd0  = (t & 3) * 16;

    // stage Q tile (64 x 64 bf16)
    {
        const ushort_t* p = Qg + ((size_t)(b * S + s0 + srow)) * E + h * DK + sd0;
        uint4 q0 = *(const uint4*)p;
        uint4 q1 = *(const uint4*)(p + 8);
        *(uint4*)&Qs[srow][sd0]     = q0;
        *(uint4*)&Qs[srow][sd0 + 8] = q1;
    }
    if (t < 64) { mrow[t] = -1e30f; lrow[t] = 0.f; }
    __syncthreads();

    const int w  = t >> 6;        // wave id: q-strip [16w, 16w+16)
    const int ln = t & 15;
    const int qd = (t >> 4) & 3;  // quad within wave
    const int m0 = w * 16;

    // Q A-fragments are loop-invariant: A[m=ln][k=qd*8+j]
    const bf16x8 aq0 = *(const bf16x8*)&Qs[m0 + ln][qd * 8];
    const bf16x8 aq1 = *(const bf16x8*)&Qs[m0 + ln][32 + qd * 8];

    f32x4 oacc[4];
    #pragma unroll
    for (int dt = 0; dt < 4; ++dt) oacc[dt] = (f32x4){0.f, 0.f, 0.f, 0.f};

    const size_t krow_base = ((size_t)(b * S)) * E + h * DK;
    const size_t vrow_base = ((size_t)bh * DK) * S;

    for (int kt = 0; kt < S / 64; ++kt) {
        // ---- stage K (64x64) and V^T (64d x 64k) ----
        {
            const ushort_t* kp = Kg + krow_base + (size_t)(kt * 64 + srow) * E + sd0;
            uint4 k0 = *(const uint4*)kp;
            uint4 k1 = *(const uint4*)(kp + 8);
            *(uint4*)&Ks[srow][sd0]     = k0;
            *(uint4*)&Ks[srow][sd0 + 8] = k1;
            const ushort_t* vp = Vtg + vrow_base + (size_t)srow * S + kt * 64 + sd0;
            uint4 v0 = *(const uint4*)vp;
            uint4 v1 = *(const uint4*)(vp + 8);
            *(uint4*)&Vs[srow][sd0]     = v0;
            *(uint4*)&Vs[srow][sd0 + 8] = v1;
        }
        __syncthreads();

        // ---- S = Q K^T (each wave: 16q x 64k strip) ----
        #pragma unroll
        for (int c = 0; c < 4; ++c) {
            f32x4 sacc = (f32x4){0.f, 0.f, 0.f, 0.f};
            bf16x8 b0 = *(const bf16x8*)&Ks[c * 16 + ln][qd * 8];
            bf16x8 b1 = *(const bf16x8*)&Ks[c * 16 + ln][32 + qd * 8];
            sacc = __builtin_amdgcn_mfma_f32_16x16x32_bf16(aq0, b0, sacc, 0, 0, 0);
            sacc = __builtin_amdgcn_mfma_f32_16x16x32_bf16(aq1, b1, sacc, 0, 0, 0);
            #pragma unroll
            for (int r = 0; r < 4; ++r)
                St[m0 + qd * 4 + r][c * 16 + ln] = sacc[r] * 0.125f;
        }
        __syncthreads();

        // ---- online softmax: 4 threads per row ----
        {
            const int r  = t >> 2;
            const int c0 = (t & 3) * 16;
            float sv[16];
            float mx = -1e30f;
            #pragma unroll
            for (int j = 0; j < 16; ++j) { sv[j] = St[r][c0 + j]; mx = fmaxf(mx, sv[j]); }
            mx = fmaxf(mx, __shfl_xor(mx, 1));
            mx = fmaxf(mx, __shfl_xor(mx, 2));
            const float m_old = mrow[r];
            const float m_new = fmaxf(m_old, mx);
            float psum = 0.f;
            #pragma unroll
            for (int j0 = 0; j0 < 16; j0 += 4) {
                float p0 = __expf(sv[j0 + 0] - m_new);
                float p1 = __expf(sv[j0 + 1] - m_new);
                float p2 = __expf(sv[j0 + 2] - m_new);
                float p3 = __expf(sv[j0 + 3] - m_new);
                psum += p0 + p1 + p2 + p3;
                ushort4 pk;
                pk.x = f2bf(p0); pk.y = f2bf(p1); pk.z = f2bf(p2); pk.w = f2bf(p3);
                *(ushort4*)&Pt[r][c0 + j0] = pk;
            }
            psum += __shfl_xor(psum, 1);
            psum += __shfl_xor(psum, 2);
            if ((t & 3) == 0) {
                const float alpha = __expf(m_old - m_new);
                lrow[r] = lrow[r] * alpha + psum;
                mrow[r] = m_new;
                arow[r] = alpha;
            }
        }
        __syncthreads();

        // ---- O = O*alpha + P V ----
        {
            float al[4];
            #pragma unroll
            for (int r = 0; r < 4; ++r) al[r] = arow[m0 + qd * 4 + r];
            #pragma unroll
            for (int dt = 0; dt < 4; ++dt)
                #pragma unroll
                for (int r = 0; r < 4; ++r) oacc[dt][r] *= al[r];
            bf16x8 p0 = *(const bf16x8*)&Pt[m0 + ln][qd * 8];
            bf16x8 p1 = *(const bf16x8*)&Pt[m0 + ln][32 + qd * 8];
            #pragma unroll
            for (int dt = 0; dt < 4; ++dt) {
                bf16x8 v0 = *(const bf16x8*)&Vs[dt * 16 + ln][qd * 8];
                bf16x8 v1 = *(const bf16x8*)&Vs[dt * 16 + ln][32 + qd * 8];
                oacc[dt] = __builtin_amdgcn_mfma_f32_16x16x32_bf16(p0, v0, oacc[dt], 0, 0, 0);
                oacc[dt] = __builtin_amdgcn_mfma_f32_16x16x32_bf16(p1, v1, oacc[dt], 0, 0, 0);
            }
        }
        __syncthreads();
    }

    // ---- epilogue: O /= l, write fp32 CTX ----
    float invl[4];
    #pragma unroll
    for (int r = 0; r < 4; ++r) invl[r] = 1.f / lrow[m0 + qd * 4 + r];
    #pragma unroll
    for (int dt = 0; dt < 4; ++dt) {
        #pragma unroll
        for (int r = 0; r < 4; ++r) {
            const size_t row = (size_t)(b * S + s0 + m0 + qd * 4 + r);
            O[row * E + h * DK + dt * 16 + ln] = oacc[dt][r] * invl[r];
        }
    }
}

// ---------------------------------------------------------------------------
extern "C" void kernel_launch(void* const* d_in, const int* in_sizes, int n_in,
                              void* d_out, int out_size, void* d_ws, size_t ws_size,
                              hipStream_t stream) {
    const float* x   = (const float*)d_in[0];
    const float* w_q = (const float*)d_in[1];
    const float* b_q = (const float*)d_in[2];
    const float* w_k = (const float*)d_in[3];
    const float* b_k = (const float*)d_in[4];
    const float* w_v = (const float*)d_in[5];
    const float* b_v = (const float*)d_in[6];
    const float* w_o = (const float*)d_in[7];
    const float* b_o = (const float*)d_in[8];
    float* out = (float*)d_out;

    ushort_t* Qw  = (ushort_t*)d_ws;                  // 16 MB bf16
    ushort_t* Kw  = Qw + (size_t)NROW * E;            // 16 MB
    ushort_t* Vtg = Kw + (size_t)NROW * E;            // 16 MB, [bh*DK+d][s]
    float*    CTX = (float*)(Vtg + (size_t)NROW * E); // 32 MB fp32

    dim3 gblk(256);
    dim3 ggrid(E / BN, NROW / BM);                    // (16, 128)

    gemm_bias_bf16_kernel   <<<ggrid, gblk, 0, stream>>>(x, w_q, b_q, Qw);
    gemm_bias_bf16_kernel   <<<ggrid, gblk, 0, stream>>>(x, w_k, b_k, Kw);
    gemm_bias_bf16_vT_kernel<<<ggrid, gblk, 0, stream>>>(x, w_v, b_v, Vtg);

    attn_mfma_kernel<<<dim3(S / 64, B * H), dim3(256), 0, stream>>>(Qw, Kw, Vtg, CTX);

    gemm_bias_kernel<<<ggrid, gblk, 0, stream>>>(CTX, w_o, b_o, out);
}

// Round 3
// 450.057 us; speedup vs baseline: 8.8879x; 2.9236x over previous
//
#include <hip/hip_runtime.h>
#include <math.h>

#define B 4
#define S 2048
#define E 1024
#define H 16
#define DK 64
#define NROW (B * S)          // 8192 rows

typedef _Float16 half_t;
typedef __attribute__((ext_vector_type(8))) _Float16 half8;
typedef __attribute__((ext_vector_type(4))) float f32x4;

__device__ __forceinline__ void gload_lds16(const void* g, void* l) {
    __builtin_amdgcn_global_load_lds((__attribute__((address_space(1))) void*)(g),
                                     (__attribute__((address_space(3))) void*)(l), 16, 0, 0);
}

// ---------------------------------------------------------------------------
// cast x (fp32 -> fp16), 8 elems/thread
// ---------------------------------------------------------------------------
__global__ __launch_bounds__(256)
void cast_x_kernel(const float* __restrict__ x, half_t* __restrict__ xh) {
    const size_t i = ((size_t)blockIdx.x * 256 + threadIdx.x) * 8;
    float4 a = *(const float4*)(x + i);
    float4 b = *(const float4*)(x + i + 4);
    half8 hv;
    hv[0] = (half_t)a.x; hv[1] = (half_t)a.y; hv[2] = (half_t)a.z; hv[3] = (half_t)a.w;
    hv[4] = (half_t)b.x; hv[5] = (half_t)b.y; hv[6] = (half_t)b.z; hv[7] = (half_t)b.w;
    *(half8*)(xh + i) = hv;
}

// ---------------------------------------------------------------------------
// cast + transpose weights: W[k][n] fp32 -> Wt[n][k] fp16 (64x64 LDS tiles)
// ---------------------------------------------------------------------------
__global__ __launch_bounds__(256)
void cast_wT_kernel(const float* __restrict__ w0, const float* __restrict__ w1,
                    const float* __restrict__ w2, const float* __restrict__ w3,
                    half_t* __restrict__ o0, half_t* __restrict__ o1,
                    half_t* __restrict__ o2, half_t* __restrict__ o3) {
    __shared__ half_t Ts[64][72];
    const int z = blockIdx.z;
    const float* W = (z == 0) ? w0 : (z == 1) ? w1 : (z == 2) ? w2 : w3;
    half_t*      O = (z == 0) ? o0 : (z == 1) ? o1 : (z == 2) ? o2 : o3;
    const int t  = threadIdx.x;
    const int k0 = blockIdx.y * 64;
    const int n0 = blockIdx.x * 64;
    const int r  = t >> 2;
    const int c0 = (t & 3) * 16;
    const float* p = W + (size_t)(k0 + r) * E + n0 + c0;
    #pragma unroll
    for (int j = 0; j < 16; j += 4) {
        float4 v = *(const float4*)(p + j);
        Ts[c0 + j + 0][r] = (half_t)v.x;
        Ts[c0 + j + 1][r] = (half_t)v.y;
        Ts[c0 + j + 2][r] = (half_t)v.z;
        Ts[c0 + j + 3][r] = (half_t)v.w;
    }
    __syncthreads();
    half_t* q = O + (size_t)(n0 + r) * E + k0 + c0;
    *(uint4*)(q)     = *(const uint4*)&Ts[r][c0];
    *(uint4*)(q + 8) = *(const uint4*)&Ts[r][c0 + 8];
}

// ---------------------------------------------------------------------------
// transpose V: Vh[(b,s)][h*64+d] fp16 -> Vt[(b*H+h)*64+d][s] fp16
// ---------------------------------------------------------------------------
__global__ __launch_bounds__(256)
void transpose_v_kernel(const half_t* __restrict__ Vh, half_t* __restrict__ Vt) {
    __shared__ half_t Ts[64][72];
    const int t  = threadIdx.x;
    const int h  = blockIdx.x;            // 16 col-tiles == heads
    const int m0 = blockIdx.y * 64;       // global row block
    const int r  = t >> 2;
    const int c0 = (t & 3) * 16;
    const half_t* p = Vh + (size_t)(m0 + r) * E + h * DK + c0;
    uint4 v0 = *(const uint4*)p;
    uint4 v1 = *(const uint4*)(p + 8);
    #pragma unroll
    for (int j = 0; j < 8; ++j) Ts[c0 + j][r]     = ((const half_t*)&v0)[j];
    #pragma unroll
    for (int j = 0; j < 8; ++j) Ts[c0 + 8 + j][r] = ((const half_t*)&v1)[j];
    __syncthreads();
    const int bb = m0 >> 11;              // batch
    const int sb = m0 & (S - 1);
    half_t* q = Vt + ((size_t)(bb * H + h) * DK + r) * S + sb + c0;
    *(uint4*)(q)     = *(const uint4*)&Ts[r][c0];
    *(uint4*)(q + 8) = *(const uint4*)&Ts[r][c0 + 8];
}

// ---------------------------------------------------------------------------
// MFMA GEMM (m97 structure): C[M,N] = A[M,K] @ Bt[N,K]^T + bias
// 128x128 tile, BK=32, 256 threads (4 waves, 2x2 of 64x64), global_load_lds.
// ---------------------------------------------------------------------------
template<bool F32OUT>
__global__ __launch_bounds__(256)
void gemm_mfma_kernel(const half_t* __restrict__ A, const half_t* __restrict__ Bt,
                      const float* __restrict__ bias, void* __restrict__ Cout) {
    __shared__ half_t As[128 * 32];
    __shared__ half_t Bs[128 * 32];
    const int t    = threadIdx.x;
    const int w    = t >> 6;
    const int lane = t & 63;
    const int ln   = t & 15;
    const int qd   = (t >> 4) & 3;
    const int bn0  = blockIdx.x * 128;
    const int bm0  = blockIdx.y * 128;
    const int wm   = (w & 1) * 64;
    const int wn   = (w >> 1) * 64;

    const int srow = lane >> 2;          // 0..15
    const int sch  = (lane & 3) * 8;     // half offset within 32-col row

    f32x4 acc[4][4];
    #pragma unroll
    for (int mi = 0; mi < 4; ++mi)
        #pragma unroll
        for (int ni = 0; ni < 4; ++ni) acc[mi][ni] = (f32x4){0.f, 0.f, 0.f, 0.f};

    for (int k0 = 0; k0 < E; k0 += 32) {
        #pragma unroll
        for (int c = 0; c < 2; ++c) {
            const int rr = c * 64 + w * 16;
            gload_lds16(A  + (size_t)(bm0 + rr + srow) * E + k0 + sch, As + rr * 32);
            gload_lds16(Bt + (size_t)(bn0 + rr + srow) * E + k0 + sch, Bs + rr * 32);
        }
        __syncthreads();
        half8 af[4], bf[4];
        #pragma unroll
        for (int mi = 0; mi < 4; ++mi) af[mi] = *(const half8*)(As + (wm + mi * 16 + ln) * 32 + qd * 8);
        #pragma unroll
        for (int ni = 0; ni < 4; ++ni) bf[ni] = *(const half8*)(Bs + (wn + ni * 16 + ln) * 32 + qd * 8);
        #pragma unroll
        for (int mi = 0; mi < 4; ++mi)
            #pragma unroll
            for (int ni = 0; ni < 4; ++ni)
                acc[mi][ni] = __builtin_amdgcn_mfma_f32_16x16x32_f16(af[mi], bf[ni], acc[mi][ni], 0, 0, 0);
        __syncthreads();
    }

    float bv[4];
    #pragma unroll
    for (int ni = 0; ni < 4; ++ni) bv[ni] = bias[bn0 + wn + ni * 16 + ln];

    #pragma unroll
    for (int mi = 0; mi < 4; ++mi) {
        #pragma unroll
        for (int r = 0; r < 4; ++r) {
            const size_t row = (size_t)(bm0 + wm + mi * 16 + qd * 4 + r);
            #pragma unroll
            for (int ni = 0; ni < 4; ++ni) {
                const size_t col = (size_t)(bn0 + wn + ni * 16 + ln);
                const float v = acc[mi][ni][r] + bv[ni];
                if (F32OUT) ((float*)Cout)[row * E + col] = v;
                else        ((half_t*)Cout)[row * E + col] = (half_t)v;
            }
        }
    }
}

// ---------------------------------------------------------------------------
// MFMA flash attention, fp16, in-register online softmax.
// Q,K fp16 row-major [row][E]; V fp16 transposed [(b*H+h)*DK+d][s]; CTX fp16.
// ---------------------------------------------------------------------------
__global__ __launch_bounds__(256)
void attn_mfma_kernel(const half_t* __restrict__ Qg, const half_t* __restrict__ Kg,
                      const half_t* __restrict__ Vtg, half_t* __restrict__ CTX) {
    __shared__ half_t Qs[64][72];
    __shared__ half_t Ks[64][72];
    __shared__ half_t Vs[64][72];
    __shared__ half_t Pt[64][72];

    const int t  = threadIdx.x;
    const int bh = blockIdx.y;
    const int b  = bh >> 4;
    const int h  = bh & 15;
    const int s0 = blockIdx.x * 64;

    const int srow = t >> 2;
    const int sd0  = (t & 3) * 16;

    {
        const half_t* p = Qg + ((size_t)(b * S + s0 + srow)) * E + h * DK + sd0;
        *(uint4*)&Qs[srow][sd0]     = *(const uint4*)p;
        *(uint4*)&Qs[srow][sd0 + 8] = *(const uint4*)(p + 8);
    }
    __syncthreads();

    const int w  = t >> 6;
    const int ln = t & 15;
    const int qd = (t >> 4) & 3;
    const int m0 = w * 16;

    const half8 aq0 = *(const half8*)&Qs[m0 + ln][qd * 8];
    const half8 aq1 = *(const half8*)&Qs[m0 + ln][32 + qd * 8];

    f32x4 oacc[4];
    #pragma unroll
    for (int dt = 0; dt < 4; ++dt) oacc[dt] = (f32x4){0.f, 0.f, 0.f, 0.f};
    float m_st[4] = {-1e30f, -1e30f, -1e30f, -1e30f};
    float l_st[4] = {0.f, 0.f, 0.f, 0.f};

    const size_t krow_base = ((size_t)(b * S)) * E + h * DK;
    const size_t vrow_base = ((size_t)bh * DK) * S;

    for (int kt = 0; kt < S / 64; ++kt) {
        {
            const half_t* kp = Kg + krow_base + (size_t)(kt * 64 + srow) * E + sd0;
            *(uint4*)&Ks[srow][sd0]     = *(const uint4*)kp;
            *(uint4*)&Ks[srow][sd0 + 8] = *(const uint4*)(kp + 8);
            const half_t* vp = Vtg + vrow_base + (size_t)srow * S + kt * 64 + sd0;
            *(uint4*)&Vs[srow][sd0]     = *(const uint4*)vp;
            *(uint4*)&Vs[srow][sd0 + 8] = *(const uint4*)(vp + 8);
        }
        __syncthreads();

        // S = Q K^T : wave strip 16q x 64k, stays in registers (C-layout)
        f32x4 sacc[4];
        #pragma unroll
        for (int c = 0; c < 4; ++c) {
            f32x4 s = (f32x4){0.f, 0.f, 0.f, 0.f};
            half8 b0 = *(const half8*)&Ks[c * 16 + ln][qd * 8];
            half8 b1 = *(const half8*)&Ks[c * 16 + ln][32 + qd * 8];
            s = __builtin_amdgcn_mfma_f32_16x16x32_f16(aq0, b0, s, 0, 0, 0);
            s = __builtin_amdgcn_mfma_f32_16x16x32_f16(aq1, b1, s, 0, 0, 0);
            #pragma unroll
            for (int r = 0; r < 4; ++r) s[r] *= 0.125f;
            sacc[c] = s;
        }

        // in-register online softmax (rows qd*4+r; butterflies within quad)
        float mnew[4], alpha[4];
        #pragma unroll
        for (int r = 0; r < 4; ++r) {
            float mx = fmaxf(fmaxf(sacc[0][r], sacc[1][r]), fmaxf(sacc[2][r], sacc[3][r]));
            #pragma unroll
            for (int off = 1; off < 16; off <<= 1) mx = fmaxf(mx, __shfl_xor(mx, off));
            mnew[r]  = fmaxf(m_st[r], mx);
            alpha[r] = __expf(m_st[r] - mnew[r]);
            m_st[r]  = mnew[r];
        }
        float rs[4] = {0.f, 0.f, 0.f, 0.f};
        #pragma unroll
        for (int c = 0; c < 4; ++c) {
            #pragma unroll
            for (int r = 0; r < 4; ++r) {
                const float pv = __expf(sacc[c][r] - mnew[r]);
                rs[r] += pv;
                Pt[m0 + qd * 4 + r][c * 16 + ln] = (half_t)pv;
            }
        }
        #pragma unroll
        for (int r = 0; r < 4; ++r) {
            float s = rs[r];
            #pragma unroll
            for (int off = 1; off < 16; off <<= 1) s += __shfl_xor(s, off);
            l_st[r] = l_st[r] * alpha[r] + s;
        }
        #pragma unroll
        for (int dt = 0; dt < 4; ++dt)
            #pragma unroll
            for (int r = 0; r < 4; ++r) oacc[dt][r] *= alpha[r];
        __syncthreads();

        // O += P V
        half8 p0 = *(const half8*)&Pt[m0 + ln][qd * 8];
        half8 p1 = *(const half8*)&Pt[m0 + ln][32 + qd * 8];
        #pragma unroll
        for (int dt = 0; dt < 4; ++dt) {
            half8 v0 = *(const half8*)&Vs[dt * 16 + ln][qd * 8];
            half8 v1 = *(const half8*)&Vs[dt * 16 + ln][32 + qd * 8];
            oacc[dt] = __builtin_amdgcn_mfma_f32_16x16x32_f16(p0, v0, oacc[dt], 0, 0, 0);
            oacc[dt] = __builtin_amdgcn_mfma_f32_16x16x32_f16(p1, v1, oacc[dt], 0, 0, 0);
        }
        __syncthreads();
    }

    #pragma unroll
    for (int r = 0; r < 4; ++r) {
        const float invl = 1.f / l_st[r];
        const size_t row = (size_t)(b * S + s0 + m0 + qd * 4 + r);
        #pragma unroll
        for (int dt = 0; dt < 4; ++dt)
            CTX[row * E + h * DK + dt * 16 + ln] = (half_t)(oacc[dt][r] * invl);
    }
}

// ---------------------------------------------------------------------------
extern "C" void kernel_launch(void* const* d_in, const int* in_sizes, int n_in,
                              void* d_out, int out_size, void* d_ws, size_t ws_size,
                              hipStream_t stream) {
    const float* x   = (const float*)d_in[0];
    const float* w_q = (const float*)d_in[1];
    const float* b_q = (const float*)d_in[2];
    const float* w_k = (const float*)d_in[3];
    const float* b_k = (const float*)d_in[4];
    const float* w_v = (const float*)d_in[5];
    const float* b_v = (const float*)d_in[6];
    const float* w_o = (const float*)d_in[7];
    const float* b_o = (const float*)d_in[8];
    float* out = (float*)d_out;

    half_t* xh  = (half_t*)d_ws;                       // 16 MB
    half_t* WtQ = xh  + (size_t)NROW * E;              // 2 MB each
    half_t* WtK = WtQ + (size_t)E * E;
    half_t* WtV = WtK + (size_t)E * E;
    half_t* WtO = WtV + (size_t)E * E;
    half_t* Qh  = WtO + (size_t)E * E;                 // 16 MB each
    half_t* Kh  = Qh  + (size_t)NROW * E;
    half_t* Vh  = Kh  + (size_t)NROW * E;
    half_t* Vt  = Vh  + (size_t)NROW * E;
    half_t* CTX = Vt  + (size_t)NROW * E;

    cast_x_kernel<<<dim3(NROW * E / (256 * 8)), dim3(256), 0, stream>>>(x, xh);
    cast_wT_kernel<<<dim3(16, 16, 4), dim3(256), 0, stream>>>(w_q, w_k, w_v, w_o,
                                                              WtQ, WtK, WtV, WtO);

    dim3 ggrid(E / 128, NROW / 128);                   // (8, 64)
    gemm_mfma_kernel<false><<<ggrid, dim3(256), 0, stream>>>(xh, WtQ, b_q, Qh);
    gemm_mfma_kernel<false><<<ggrid, dim3(256), 0, stream>>>(xh, WtK, b_k, Kh);
    gemm_mfma_kernel<false><<<ggrid, dim3(256), 0, stream>>>(xh, WtV, b_v, Vh);

    transpose_v_kernel<<<dim3(16, NROW / 64), dim3(256), 0, stream>>>(Vh, Vt);

    attn_mfma_kernel<<<dim3(S / 64, B * H), dim3(256), 0, stream>>>(Qh, Kh, Vt, CTX);

    gemm_mfma_kernel<true><<<ggrid, dim3(256), 0, stream>>>(CTX, WtO, b_o, out);
}